// Round 9
// baseline (266.620 us; speedup 1.0000x reference)
//
#include <hip/hip_runtime.h>

// HiLo attention (B=8, DIM=512, 64x64, ws=2, 4 hi heads + 4 lo heads, hd=64).
// FP32 I/O, bf16 MFMA compute with fp32 accumulation.
// R8: lofi_flash kv-split=2 (deferred softmax => partials are pure sums):
//     grid z=2 halves of kv, bf16 partial O + fp32 partial l, combine kernel
//     normalizes in place. Occupancy 4 -> 5 blocks/CU + halved tail.

typedef __attribute__((ext_vector_type(8))) short bf16x8;
typedef __attribute__((ext_vector_type(4))) float f32x4;
typedef __attribute__((ext_vector_type(4))) unsigned short us4;
typedef __attribute__((ext_vector_type(2))) unsigned int u32x2;

static __device__ __forceinline__ float bf2f(unsigned short u){
  unsigned int x = ((unsigned int)u) << 16; float f; __builtin_memcpy(&f, &x, 4); return f;
}
static __device__ __forceinline__ unsigned short f2bf(float f){
  unsigned int x; __builtin_memcpy(&x, &f, 4);
  x += 0x7fffu + ((x >> 16) & 1u);          // RNE
  return (unsigned short)(x >> 16);
}

// async 16B global->LDS (dest = wave-uniform base + lane*16)
static __device__ __forceinline__ void gload_lds16(const void* g, void* l){
  __builtin_amdgcn_global_load_lds(
      (const __attribute__((address_space(1))) unsigned int*)g,
      (__attribute__((address_space(3))) unsigned int*)l,
      16, 0, 0);
}

// swizzled ushort index within a [rows][64]-ushort LDS tile (lofi_flash):
static __device__ __forceinline__ int swz(int row, int colu){
  return row*64 + (colu ^ ((row & 7) << 3));
}

// ---------------------------------------------------------------------------
// All 5 weight matrices fp32 -> bf16 in one launch.
// ---------------------------------------------------------------------------
__global__ void cvt_weights(const float* __restrict__ w0, const float* __restrict__ w1,
                            const float* __restrict__ w2, const float* __restrict__ w3,
                            const float* __restrict__ w4,
                            unsigned short* __restrict__ d0, unsigned short* __restrict__ d1,
                            unsigned short* __restrict__ d2, unsigned short* __restrict__ d3,
                            unsigned short* __restrict__ d4)
{
  int i = (int)(blockIdx.x*256 + threadIdx.x);      // [0, 229376)
  const float* src; unsigned short* dst; int j;
  if      (i < 98304) { src = w0; dst = d0; j = i; }
  else if (i < 131072){ src = w1; dst = d1; j = i - 98304; }
  else if (i < 196608){ src = w2; dst = d2; j = i - 131072; }
  else if (i < 212992){ src = w3; dst = d3; j = i - 196608; }
  else                { src = w4; dst = d4; j = i - 212992; }
  f32x4 v = *(const f32x4*)(src + (long)j*4);
  us4 o;
  #pragma unroll
  for (int q = 0; q < 4; q++) o[q] = f2bf(v[q]);
  *(us4*)(dst + (long)j*4) = o;
}

// ---------------------------------------------------------------------------
// Generic bf16 GEMM:  C[row][col] = sum_k A[row][k] * B[col][k]  (A@B^T form)
// Staging via global_load_lds width=16 into linear [rows][32] LDS (R7 green).
// ---------------------------------------------------------------------------
template<int BM,int BN,int WM,int WN,bool OUT_T,bool OUT_F32>
__global__ __launch_bounds__(WM*WN*64)
void gemm_bt(const unsigned short* __restrict__ A, const unsigned short* __restrict__ B,
             const float* __restrict__ bias, void* __restrict__ Cv,
             int K, int lda, int ldb, int ldc,
             int NB, int z0,
             long sAb, long sAn, long sAz,
             long sBb, long sBn, long sBz,
             long sCb, long sCn, long sCz)
{
  constexpr int NW = WM*WN;                     // waves per block (=4 here)
  __shared__ __attribute__((aligned(16))) unsigned short lA[BM*32];
  __shared__ __attribute__((aligned(16))) unsigned short lB[BN*32];
  const int tid  = threadIdx.x;
  const int lane = tid & 63;
  const int wave = tid >> 6;
  const int wm = wave / WN, wn = wave % WN;
  const int zz = z0 + (int)blockIdx.z;
  const int zb = zz / NB, zn = zz % NB;
  const unsigned short* Ab = A + zb*sAb + zn*sAn + (long)blockIdx.z*sAz + (long)blockIdx.x*BM*lda;
  const unsigned short* Bb = B + zb*sBb + zn*sBn + (long)blockIdx.z*sBz + (long)blockIdx.y*BN*ldb;
  const long cOff = zb*sCb + zn*sCn + (long)blockIdx.z*sCz;

  const int srow = wave*16 + (lane >> 2);       // staging row within 64-row group
  const int scol = (lane & 3) * 8;              // staging k-offset (elements)

  f32x4 acc[4][4] = {};
  const int kq = (lane >> 4) * 8;
  const int lr = lane & 15;
  for (int k0 = 0; k0 < K; k0 += 32){
    if (k0) __syncthreads();
    #pragma unroll
    for (int i = 0; i < BM/(NW*16); i++)
      gload_lds16(Ab + (long)(i*NW*16 + srow)*lda + k0 + scol,
                  &lA[(i*NW*16 + wave*16)*32]);
    #pragma unroll
    for (int i = 0; i < BN/(NW*16); i++)
      gload_lds16(Bb + (long)(i*NW*16 + srow)*ldb + k0 + scol,
                  &lB[(i*NW*16 + wave*16)*32]);
    __syncthreads();                            // compiler drains vmcnt here
    bf16x8 af[4], bfr[4];
    #pragma unroll
    for (int i = 0; i < 4; i++)
      af[i]  = *(const bf16x8*)(&lA[(wm*64 + i*16 + lr)*32 + kq]);
    #pragma unroll
    for (int j = 0; j < 4; j++)
      bfr[j] = *(const bf16x8*)(&lB[(wn*64 + j*16 + lr)*32 + kq]);
    #pragma unroll
    for (int i = 0; i < 4; i++)
      #pragma unroll
      for (int j = 0; j < 4; j++)
        acc[i][j] = __builtin_amdgcn_mfma_f32_16x16x32_bf16(af[i], bfr[j], acc[i][j], 0, 0, 0);
  }
  const int row0 = (int)blockIdx.x*BM + wm*64;
  const int col0 = (int)blockIdx.y*BN + wn*64;
  #pragma unroll
  for (int j = 0; j < 4; j++){
    const int c = col0 + j*16 + (lane & 15);
    const float bv = bias ? bias[c] : 0.f;
    #pragma unroll
    for (int i = 0; i < 4; i++){
      const int r = row0 + i*16 + ((lane >> 4) << 2);
      f32x4 v = acc[i][j];
      if (OUT_T && OUT_F32){
        float* Cf = (float*)Cv + cOff;
        f32x4 w;
        #pragma unroll
        for (int q = 0; q < 4; q++) w[q] = v[q] + bv;
        *(f32x4*)(Cf + (long)c*ldc + r) = w;          // r%4==0 -> 16B aligned
      } else {
        unsigned short* Cb = (unsigned short*)Cv + cOff;
        #pragma unroll
        for (int q = 0; q < 4; q++) Cb[(long)(r + q)*ldc + c] = f2bf(v[q] + bv);
      }
    }
  }
}

// ---------------------------------------------------------------------------
// x fp32 (B,512,4096) -> xT bf16 (B,4096,512)    64x64 tiles through LDS
// ---------------------------------------------------------------------------
__global__ void transpose_xT(const float* __restrict__ x, unsigned short* __restrict__ xT)
{
  __shared__ __attribute__((aligned(16))) unsigned short t[64][72];
  const int tid = threadIdx.x;
  const int b = blockIdx.z, ct = blockIdx.y, pt = blockIdx.x;
  const long c0 = (long)ct*64, p0 = (long)pt*64;
  const float* src = x + ((long)b*512 + c0)*4096 + p0;
  for (int s = tid; s < 1024; s += 256){
    int cl = s >> 4, seg = s & 15;
    f32x4 v = *(const f32x4*)(src + (long)cl*4096 + seg*4);
    us4 o;
    #pragma unroll
    for (int q = 0; q < 4; q++) o[q] = f2bf(v[q]);
    *(us4*)(&t[cl][seg*4]) = o;
  }
  __syncthreads();
  unsigned short* dst = xT + ((long)b*4096 + p0)*512 + c0;
  for (int s = tid; s < 512; s += 256){
    int pl = s >> 3, seg = s & 7;
    unsigned short w[8];
    #pragma unroll
    for (int q = 0; q < 8; q++) w[q] = t[seg*8 + q][pl];
    *(bf16x8*)(dst + (long)pl*512 + seg*8) = *(bf16x8*)w;
  }
}

// ---------------------------------------------------------------------------
// AvgPool2d(2,2) on xT: xT (B,4096,512) -> xp (B,1024,512)   (bf16)
// ---------------------------------------------------------------------------
__global__ void pool_xT(const unsigned short* __restrict__ xT, unsigned short* __restrict__ xp)
{
  long idx = (long)blockIdx.x*256 + threadIdx.x;
  int cseg = (int)(idx & 63);
  int m    = (int)((idx >> 6) & 1023);
  int b    = (int)(idx >> 16);
  int gh = m >> 5, gw = m & 31;
  long p = (long)(gh*2)*64 + gw*2;
  const unsigned short* src = xT + ((long)b*4096 + p)*512 + cseg*8;
  bf16x8 r0 = *(const bf16x8*)(src);
  bf16x8 r1 = *(const bf16x8*)(src + 512);
  bf16x8 r2 = *(const bf16x8*)(src + 64*512);
  bf16x8 r3 = *(const bf16x8*)(src + 65*512);
  unsigned short o[8];
  #pragma unroll
  for (int q = 0; q < 8; q++)
    o[q] = f2bf((bf2f((unsigned short)r0[q]) + bf2f((unsigned short)r1[q]) +
                 bf2f((unsigned short)r2[q]) + bf2f((unsigned short)r3[q])) * 0.25f);
  *(bf16x8*)(xp + ((long)b*1024 + m)*512 + cseg*8) = *(bf16x8*)o;
}

// ---------------------------------------------------------------------------
// lkv (B,1024,512) V-half -> vT (B*4, 64, 1024), columns PERMUTED within each
// 64-kv tile: stored col c holds kv = invperm(c) = (c>>2) + (c&3)*16.
// ---------------------------------------------------------------------------
__global__ void transpose_vT(const unsigned short* __restrict__ lkv, unsigned short* __restrict__ vT)
{
  __shared__ __attribute__((aligned(16))) unsigned short t[64][72];
  const int tid = threadIdx.x;
  const int pair = blockIdx.y;              // b*4+n
  const int b = pair >> 2, n = pair & 3;
  const long m0 = (long)blockIdx.x*64;      // 64-aligned kv tile base
  const unsigned short* src = lkv + ((long)b*1024 + m0)*512 + 256 + n*64;
  for (int s = tid; s < 512; s += 256){
    int ml = s >> 3, seg = s & 7;
    bf16x8 v = *(const bf16x8*)(src + (long)ml*512 + seg*8);
    *(bf16x8*)(&t[ml][seg*8]) = v;
  }
  __syncthreads();
  unsigned short* dst = vT + (long)pair*64*1024 + m0;
  for (int s = tid; s < 512; s += 256){
    int dl = s >> 3, seg = s & 7;
    unsigned short w[8];
    #pragma unroll
    for (int q = 0; q < 8; q++)
      w[q] = t[(q & 3)*16 + seg*2 + (q >> 2)][dl];   // kv = invperm(seg*8+q)
    *(bf16x8*)(dst + (long)dl*1024 + seg*8) = *(bf16x8*)w;
  }
}

// ---------------------------------------------------------------------------
// Hi-fi window attention, batched over blockIdx.y batches.
// ---------------------------------------------------------------------------
__global__ void hifi_attn(const unsigned short* __restrict__ qkv, unsigned short* __restrict__ out)
{
  const int gwv  = (int)((blockIdx.x*blockDim.x + threadIdx.x) >> 6);
  const int lane = threadIdx.x & 63;
  const int n = gwv & 3;
  const int g = gwv >> 2;
  const long bb = (long)blockIdx.y;
  const unsigned short* base = qkv + bb*4096*768 + (long)g*4*768 + n*64 + lane;
  float q[4], k[4], v[4];
  #pragma unroll
  for (int t = 0; t < 4; t++){
    q[t] = bf2f(base[t*768]);
    k[t] = bf2f(base[t*768 + 256]);
    v[t] = bf2f(base[t*768 + 512]);
  }
  float S[4][4];
  #pragma unroll
  for (int i = 0; i < 4; i++)
    #pragma unroll
    for (int j = 0; j < 4; j++){
      float s = q[i]*k[j];
      #pragma unroll
      for (int off = 32; off; off >>= 1) s += __shfl_xor(s, off);
      S[i][j] = s;
    }
  const int gh = g >> 5, gwd = g & 31;
  unsigned short* ob = out + bb*4096*256 + n*64 + lane;
  #pragma unroll
  for (int t = 0; t < 4; t++){
    float m = fmaxf(fmaxf(S[t][0], S[t][1]), fmaxf(S[t][2], S[t][3]));
    float e0 = __expf((S[t][0]-m)*0.125f);
    float e1 = __expf((S[t][1]-m)*0.125f);
    float e2 = __expf((S[t][2]-m)*0.125f);
    float e3 = __expf((S[t][3]-m)*0.125f);
    float inv = 1.f / (e0+e1+e2+e3);
    float o = (e0*v[0] + e1*v[1] + e2*v[2] + e3*v[3]) * inv;
    int y = gh*2 + (t >> 1), xx = gwd*2 + (t & 1);
    ob[(long)(y*64 + xx)*256] = f2bf(o);
  }
}

// ---------------------------------------------------------------------------
// Fused lo-fi flash attention, kv-SPLIT over blockIdx.z (2 halves of 512 kv).
// Deferred softmax => partials are pure sums: Opart[s] (bf16, attnl layout),
// lpart[s] (fp32). Grid (32 q-tiles, 32 pairs, 2 splits), 256 threads.
// ---------------------------------------------------------------------------
__global__ __launch_bounds__(256, 4)
void lofi_flash(const unsigned short* __restrict__ lq,
                const unsigned short* __restrict__ lkv,
                const unsigned short* __restrict__ vT,
                unsigned short* __restrict__ Opart,
                float* __restrict__ lpart)
{
  __shared__ __attribute__((aligned(16))) unsigned short Klds[64*64];
  __shared__ __attribute__((aligned(16))) unsigned short Vlds[64*64];
  __shared__ __attribute__((aligned(16))) unsigned short Plds[128*64];
  const int tid  = threadIdx.x;
  const int lane = tid & 63;
  const int wave = tid >> 6;
  const int pair = blockIdx.y;              // b*4+n
  const int b = pair >> 2, n = pair & 3;
  const int sp = (int)blockIdx.z;           // kv split [0,2)
  const int kvbase = sp*512;
  const int wq0 = (int)blockIdx.x*128 + wave*32;
  const int lr = lane & 15;
  const int lg = lane >> 4;

  const unsigned short* Qbase = lq + ((long)b*4096 + wq0)*256 + n*64;
  bf16x8 qf[2][2];
  #pragma unroll
  for (int mi = 0; mi < 2; mi++)
    #pragma unroll
    for (int kk = 0; kk < 2; kk++)
      qf[mi][kk] = *(const bf16x8*)(Qbase + (long)(mi*16 + lr)*256 + kk*32 + lg*8);

  f32x4 Oacc[2][4] = {};
  float psum[2][4] = {};                    // per-lane partial row sums

  const unsigned short* Kg = lkv + (long)b*1024*512 + n*64 + (long)kvbase*512;
  const unsigned short* Vg = vT + (long)pair*64*1024 + kvbase;

  // async reg-staged K/V: each thread owns rows (rK, rK+32), seg sg
  const int rK = tid >> 3;
  const int sg = (tid & 7) * 8;
  bf16x8 k0, k1, v0, v1;
  {
    k0 = *(const bf16x8*)(Kg + (long)rK*512 + sg);
    k1 = *(const bf16x8*)(Kg + (long)(rK + 32)*512 + sg);
    v0 = *(const bf16x8*)(Vg + (long)rK*1024 + sg);
    v1 = *(const bf16x8*)(Vg + (long)(rK + 32)*1024 + sg);
  }

  for (int t = 0; t < 8; t++){
    __syncthreads();
    *(bf16x8*)(&Klds[swz(rK, sg)])      = k0;
    *(bf16x8*)(&Klds[swz(rK + 32, sg)]) = k1;
    *(bf16x8*)(&Vlds[swz(rK, sg)])      = v0;
    *(bf16x8*)(&Vlds[swz(rK + 32, sg)]) = v1;
    __syncthreads();
    if (t < 7){
      const int kv1 = (t + 1)*64;
      k0 = *(const bf16x8*)(Kg + (long)(kv1 + rK)*512 + sg);
      k1 = *(const bf16x8*)(Kg + (long)(kv1 + rK + 32)*512 + sg);
      v0 = *(const bf16x8*)(Vg + (long)rK*1024 + kv1 + sg);
      v1 = *(const bf16x8*)(Vg + (long)(rK + 32)*1024 + kv1 + sg);
    }
    // S = Q @ K^T (wave's 32 q x 64 kv)
    f32x4 S[2][4] = {};
    bf16x8 kf[4][2];
    #pragma unroll
    for (int nj = 0; nj < 4; nj++)
      #pragma unroll
      for (int kk = 0; kk < 2; kk++)
        kf[nj][kk] = *(const bf16x8*)(&Klds[swz(nj*16 + lr, kk*32 + lg*8)]);
    #pragma unroll
    for (int mi = 0; mi < 2; mi++)
      #pragma unroll
      for (int nj = 0; nj < 4; nj++)
        #pragma unroll
        for (int kk = 0; kk < 2; kk++)
          S[mi][nj] = __builtin_amdgcn_mfma_f32_16x16x32_bf16(qf[mi][kk], kf[nj][kk], S[mi][nj], 0, 0, 0);
    // P = exp2(S*scale*log2e); packed stash at permuted cols lr*4+nj.
    #pragma unroll
    for (int mi = 0; mi < 2; mi++){
      #pragma unroll
      for (int rg = 0; rg < 4; rg++){
        float e0 = exp2f(S[mi][0][rg]*0.1803368801f);
        float e1 = exp2f(S[mi][1][rg]*0.1803368801f);
        float e2 = exp2f(S[mi][2][rg]*0.1803368801f);
        float e3 = exp2f(S[mi][3][rg]*0.1803368801f);
        psum[mi][rg] += (e0 + e1) + (e2 + e3);
        unsigned int plo, phi;
        asm("v_cvt_pk_bf16_f32 %0, %1, %2" : "=v"(plo) : "v"(e0), "v"(e1));
        asm("v_cvt_pk_bf16_f32 %0, %1, %2" : "=v"(phi) : "v"(e2), "v"(e3));
        int prow = wave*32 + mi*16 + lg*4 + rg;
        u32x2 pk; pk[0] = plo; pk[1] = phi;
        *(u32x2*)(&Plds[swz(prow, lr*4)]) = pk;
      }
    }
    // PV: O += P @ V   (P cols and V cols share the same kv permutation)
    bf16x8 pf[2][2], vf[4][2];
    #pragma unroll
    for (int mi = 0; mi < 2; mi++)
      #pragma unroll
      for (int kk = 0; kk < 2; kk++)
        pf[mi][kk] = *(const bf16x8*)(&Plds[swz(wave*32 + mi*16 + lr, kk*32 + lg*8)]);
    #pragma unroll
    for (int dj = 0; dj < 4; dj++)
      #pragma unroll
      for (int kk = 0; kk < 2; kk++)
        vf[dj][kk] = *(const bf16x8*)(&Vlds[swz(dj*16 + lr, kk*32 + lg*8)]);
    #pragma unroll
    for (int mi = 0; mi < 2; mi++)
      #pragma unroll
      for (int dj = 0; dj < 4; dj++)
        #pragma unroll
        for (int kk = 0; kk < 2; kk++)
          Oacc[mi][dj] = __builtin_amdgcn_mfma_f32_16x16x32_bf16(pf[mi][kk], vf[dj][kk], Oacc[mi][dj], 0, 0, 0);
  }
  // final partial row-sum reduce across the 16 col-lanes (lr dimension)
  #pragma unroll
  for (int mi = 0; mi < 2; mi++)
    #pragma unroll
    for (int rg = 0; rg < 4; rg++){
      float s = psum[mi][rg];
      #pragma unroll
      for (int off = 1; off < 16; off <<= 1) s += __shfl_xor(s, off);
      psum[mi][rg] = s;
    }
  // epilogue: unnormalized O partial -> Opart[sp]; row sums -> lpart[sp]
  unsigned short* Ob = Opart + (long)sp*8388608 + ((long)b*4096 + wq0)*256 + n*64;
  #pragma unroll
  for (int mi = 0; mi < 2; mi++)
    #pragma unroll
    for (int rg = 0; rg < 4; rg++){
      int r = mi*16 + lg*4 + rg;
      #pragma unroll
      for (int dj = 0; dj < 4; dj++)
        Ob[(long)r*256 + dj*16 + lr] = f2bf(Oacc[mi][dj][rg]);
    }
  float* lp = lpart + ((long)sp*32 + pair)*4096 + wq0;
  if (lr == 0){
    #pragma unroll
    for (int mi = 0; mi < 2; mi++)
      #pragma unroll
      for (int rg = 0; rg < 4; rg++)
        lp[mi*16 + lg*4 + rg] = psum[mi][rg];
  }
}

// ---------------------------------------------------------------------------
// Combine: attnl = (O0 + O1) / (l0 + l1), in place over O0. 1 bf16x8/thread.
// ---------------------------------------------------------------------------
__global__ void lofi_combine(unsigned short* __restrict__ O0,
                             const unsigned short* __restrict__ O1,
                             const float* __restrict__ lpart)
{
  long e = ((long)blockIdx.x*256 + threadIdx.x) * 8;   // elem base, < 8388608
  int q = (int)((e >> 8) & 4095);
  int b = (int)(e >> 20);
  int n = (int)((e >> 6) & 3);
  int pair = b*4 + n;
  float l0 = lpart[(long)pair*4096 + q];
  float l1 = lpart[(long)(32 + pair)*4096 + q];
  float inv = 1.f / (l0 + l1);
  bf16x8 a = *(const bf16x8*)(O0 + e);
  bf16x8 c = *(const bf16x8*)(O1 + e);
  unsigned short o[8];
  #pragma unroll
  for (int j = 0; j < 8; j++)
    o[j] = f2bf((bf2f((unsigned short)a[j]) + bf2f((unsigned short)c[j])) * inv);
  *(bf16x8*)(O0 + e) = *(bf16x8*)o;
}

// ---------------------------------------------------------------------------
extern "C" void kernel_launch(void* const* d_in, const int* in_sizes, int n_in,
                              void* d_out, int out_size, void* d_ws, size_t ws_size,
                              hipStream_t stream)
{
  (void)in_sizes; (void)n_in; (void)out_size;
  const float* x      = (const float*)d_in[0];
  const float* Whqkv  = (const float*)d_in[1];
  const float* bhqkv  = (const float*)d_in[2];
  const float* Whproj = (const float*)d_in[3];
  const float* bhproj = (const float*)d_in[4];
  const float* Wlq    = (const float*)d_in[5];
  const float* blq    = (const float*)d_in[6];
  const float* Wlkv   = (const float*)d_in[7];
  const float* blkv   = (const float*)d_in[8];
  const float* Wlproj = (const float*)d_in[9];
  const float* blproj = (const float*)d_in[10];
  float* out = (float*)d_out;
  char* ws = (char*)d_ws;

  // Layout (bytes), peak touched 73,138,176 (same guard as green R7):
  //  stage A (hi-fi): xT [0,32M) ; qkvh_c [32M,57.2M) ; attnh_c [57.2M,65.6M)
  //  stage B (lo-fi): lqb [32M,48M) ; xp [48M,56M) ; lkvb [56M,64M) ;
  //    vTb [64M,68M) ; Opart0/attnl [0,16M) ; Opart1 [16M,32M) (xT dead) ;
  //    lpart [48M, +1.05M) (xp dead)
  //  weights tail [71.3M, 73.1M)
  if (ws_size < 73138176u) return;
  unsigned short* xT      = (unsigned short*)(ws + 0);
  unsigned short* attnl   = (unsigned short*)(ws + 0);          // = Opart0
  unsigned short* Opart1  = (unsigned short*)(ws + 16777216L);
  unsigned short* qkvh_c  = (unsigned short*)(ws + 33554432L);
  unsigned short* attnh_c = (unsigned short*)(ws + 58720256L);
  unsigned short* lqb     = (unsigned short*)(ws + 33554432L);
  unsigned short* xp      = (unsigned short*)(ws + 50331648L);
  float*          lpart   = (float*)         (ws + 50331648L);  // xp dead by lofi
  unsigned short* lkvb    = (unsigned short*)(ws + 58720256L);
  unsigned short* vTb     = (unsigned short*)(ws + 67108864L);
  unsigned short* Whqkv_b = (unsigned short*)(ws + 71303168L);
  unsigned short* Wlq_b   = (unsigned short*)(ws + 72089600L);
  unsigned short* Wlkv_b  = (unsigned short*)(ws + 72351744L);
  unsigned short* Whproj_b= (unsigned short*)(ws + 72876032L);
  unsigned short* Wlproj_b= (unsigned short*)(ws + 73007104L);

  // 0) all weights fp32 -> bf16 (one launch)
  cvt_weights<<<896, 256, 0, stream>>>(Whqkv, Wlq, Wlkv, Whproj, Wlproj,
                                       Whqkv_b, Wlq_b, Wlkv_b, Whproj_b, Wlproj_b);

  // 1) x -> xT (spatial-major, bf16)
  transpose_xT<<<dim3(64,8,8),256,0,stream>>>(x, xT);

  // 2) hi-fi path, 2 chunks of 4 batches
  for (int c = 0; c < 2; c++){
    const unsigned short* xTc = xT + (long)c*4*4096*512;
    gemm_bt<128,128,2,2,false,false><<<dim3(32,6,4),256,0,stream>>>(xTc, Whqkv_b, bhqkv, qkvh_c,
        512, 512, 512, 768, 1, 0,
        0, 0, 4096L*512,   0, 0, 0,   0, 0, 4096L*768);
    hifi_attn<<<dim3(1024,4),256,0,stream>>>(qkvh_c, attnh_c);
    gemm_bt<128,128,2,2,true,true><<<dim3(32,2,4),256,0,stream>>>(attnh_c, Whproj_b, bhproj,
        out + (long)c*4*512*4096,
        256, 256, 256, 4096, 1, 0,
        0, 0, 4096L*256,   0, 0, 0,   0, 0, 512L*4096);
  }

  // 3) lq = xT @ W_lq^T + b   (B,4096,256)
  gemm_bt<128,128,2,2,false,false><<<dim3(32,2,8),256,0,stream>>>(xT, Wlq_b, blq, lqb,
      512, 512, 512, 256, 1, 0,
      4096L*512, 0, 0,   0, 0, 0,   4096L*256, 0, 0);
  // 4) avgpool -> xp (B,1024,512)
  pool_xT<<<2048,256,0,stream>>>(xT, xp);
  // 5) lkv = xp @ W_lkv^T + b (B,1024,512)
  gemm_bt<128,128,2,2,false,false><<<dim3(8,4,8),256,0,stream>>>(xp, Wlkv_b, blkv, lkvb,
      512, 512, 512, 512, 1, 0,
      1024L*512, 0, 0,   0, 0, 0,   1024L*512, 0, 0);
  // 6) V^T per (b,head), kv-permuted columns: (32,64,1024)
  transpose_vT<<<dim3(16,32),256,0,stream>>>(lkvb, vTb);
  // 7) lo-fi flash attention, kv-split=2 (xT dead -> Opart0/1, xp -> lpart)
  lofi_flash<<<dim3(32,32,2),256,0,stream>>>(lqb, lkvb, vTb, attnl, lpart);
  // 7b) combine partials -> attnl (in place over Opart0)
  lofi_combine<<<4096,256,0,stream>>>(attnl, Opart1, lpart);
  // 8) x_l = attnl @ W_lproj^T + b -> d_out channels [256,512), batched
  gemm_bt<128,128,2,2,true,true><<<dim3(32,2,8),256,0,stream>>>(attnl, Wlproj_b, blproj,
      out + 256L*4096,
      256, 256, 256, 4096, 1, 0,
      4096L*256, 0, 0,   0, 0, 0,   512L*4096, 0, 0);
}

// Round 10
// 240.737 us; speedup vs baseline: 1.1075x; 1.1075x over previous
//
#include <hip/hip_runtime.h>

// HiLo attention (B=8, DIM=512, 64x64, ws=2, 4 hi heads + 4 lo heads, hd=64).
// FP32 I/O, bf16 MFMA compute with fp32 accumulation.
// R9: revert kv-split (regressed). lofi_flash: swapped QK^T (S=mfma(K,Q)) +
//     kv-permutation pi so P packs in-register into PV A-frags via
//     v_cvt_pk_bf16_f32 -> P LDS bounce deleted, Plds deleted (LDS 16KB).
//     transpose_vT emits pi-ordered V columns (free).

typedef __attribute__((ext_vector_type(8))) short bf16x8;
typedef __attribute__((ext_vector_type(4))) float f32x4;
typedef __attribute__((ext_vector_type(4))) unsigned short us4;
typedef __attribute__((ext_vector_type(4))) unsigned int u32x4;

static __device__ __forceinline__ float bf2f(unsigned short u){
  unsigned int x = ((unsigned int)u) << 16; float f; __builtin_memcpy(&f, &x, 4); return f;
}
static __device__ __forceinline__ unsigned short f2bf(float f){
  unsigned int x; __builtin_memcpy(&x, &f, 4);
  x += 0x7fffu + ((x >> 16) & 1u);          // RNE
  return (unsigned short)(x >> 16);
}

// async 16B global->LDS (dest = wave-uniform base + lane*16)
static __device__ __forceinline__ void gload_lds16(const void* g, void* l){
  __builtin_amdgcn_global_load_lds(
      (const __attribute__((address_space(1))) unsigned int*)g,
      (__attribute__((address_space(3))) unsigned int*)l,
      16, 0, 0);
}

// swizzled ushort index within a [rows][64]-ushort LDS tile:
static __device__ __forceinline__ int swz(int row, int colu){
  return row*64 + (colu ^ ((row & 7) << 3));
}

// ---------------------------------------------------------------------------
// All 5 weight matrices fp32 -> bf16 in one launch.
// ---------------------------------------------------------------------------
__global__ void cvt_weights(const float* __restrict__ w0, const float* __restrict__ w1,
                            const float* __restrict__ w2, const float* __restrict__ w3,
                            const float* __restrict__ w4,
                            unsigned short* __restrict__ d0, unsigned short* __restrict__ d1,
                            unsigned short* __restrict__ d2, unsigned short* __restrict__ d3,
                            unsigned short* __restrict__ d4)
{
  int i = (int)(blockIdx.x*256 + threadIdx.x);      // [0, 229376)
  const float* src; unsigned short* dst; int j;
  if      (i < 98304) { src = w0; dst = d0; j = i; }
  else if (i < 131072){ src = w1; dst = d1; j = i - 98304; }
  else if (i < 196608){ src = w2; dst = d2; j = i - 131072; }
  else if (i < 212992){ src = w3; dst = d3; j = i - 196608; }
  else                { src = w4; dst = d4; j = i - 212992; }
  f32x4 v = *(const f32x4*)(src + (long)j*4);
  us4 o;
  #pragma unroll
  for (int q = 0; q < 4; q++) o[q] = f2bf(v[q]);
  *(us4*)(dst + (long)j*4) = o;
}

// ---------------------------------------------------------------------------
// Generic bf16 GEMM:  C[row][col] = sum_k A[row][k] * B[col][k]  (A@B^T form)
// Staging via global_load_lds width=16 into linear [rows][32] LDS (R7 green).
// ---------------------------------------------------------------------------
template<int BM,int BN,int WM,int WN,bool OUT_T,bool OUT_F32>
__global__ __launch_bounds__(WM*WN*64)
void gemm_bt(const unsigned short* __restrict__ A, const unsigned short* __restrict__ B,
             const float* __restrict__ bias, void* __restrict__ Cv,
             int K, int lda, int ldb, int ldc,
             int NB, int z0,
             long sAb, long sAn, long sAz,
             long sBb, long sBn, long sBz,
             long sCb, long sCn, long sCz)
{
  constexpr int NW = WM*WN;                     // waves per block (=4 here)
  __shared__ __attribute__((aligned(16))) unsigned short lA[BM*32];
  __shared__ __attribute__((aligned(16))) unsigned short lB[BN*32];
  const int tid  = threadIdx.x;
  const int lane = tid & 63;
  const int wave = tid >> 6;
  const int wm = wave / WN, wn = wave % WN;
  const int zz = z0 + (int)blockIdx.z;
  const int zb = zz / NB, zn = zz % NB;
  const unsigned short* Ab = A + zb*sAb + zn*sAn + (long)blockIdx.z*sAz + (long)blockIdx.x*BM*lda;
  const unsigned short* Bb = B + zb*sBb + zn*sBn + (long)blockIdx.z*sBz + (long)blockIdx.y*BN*ldb;
  const long cOff = zb*sCb + zn*sCn + (long)blockIdx.z*sCz;

  const int srow = wave*16 + (lane >> 2);       // staging row within 64-row group
  const int scol = (lane & 3) * 8;              // staging k-offset (elements)

  f32x4 acc[4][4] = {};
  const int kq = (lane >> 4) * 8;
  const int lr = lane & 15;
  for (int k0 = 0; k0 < K; k0 += 32){
    if (k0) __syncthreads();
    #pragma unroll
    for (int i = 0; i < BM/(NW*16); i++)
      gload_lds16(Ab + (long)(i*NW*16 + srow)*lda + k0 + scol,
                  &lA[(i*NW*16 + wave*16)*32]);
    #pragma unroll
    for (int i = 0; i < BN/(NW*16); i++)
      gload_lds16(Bb + (long)(i*NW*16 + srow)*ldb + k0 + scol,
                  &lB[(i*NW*16 + wave*16)*32]);
    __syncthreads();                            // compiler drains vmcnt here
    bf16x8 af[4], bfr[4];
    #pragma unroll
    for (int i = 0; i < 4; i++)
      af[i]  = *(const bf16x8*)(&lA[(wm*64 + i*16 + lr)*32 + kq]);
    #pragma unroll
    for (int j = 0; j < 4; j++)
      bfr[j] = *(const bf16x8*)(&lB[(wn*64 + j*16 + lr)*32 + kq]);
    #pragma unroll
    for (int i = 0; i < 4; i++)
      #pragma unroll
      for (int j = 0; j < 4; j++)
        acc[i][j] = __builtin_amdgcn_mfma_f32_16x16x32_bf16(af[i], bfr[j], acc[i][j], 0, 0, 0);
  }
  const int row0 = (int)blockIdx.x*BM + wm*64;
  const int col0 = (int)blockIdx.y*BN + wn*64;
  #pragma unroll
  for (int j = 0; j < 4; j++){
    const int c = col0 + j*16 + (lane & 15);
    const float bv = bias ? bias[c] : 0.f;
    #pragma unroll
    for (int i = 0; i < 4; i++){
      const int r = row0 + i*16 + ((lane >> 4) << 2);
      f32x4 v = acc[i][j];
      if (OUT_T && OUT_F32){
        float* Cf = (float*)Cv + cOff;
        f32x4 w;
        #pragma unroll
        for (int q = 0; q < 4; q++) w[q] = v[q] + bv;
        *(f32x4*)(Cf + (long)c*ldc + r) = w;          // r%4==0 -> 16B aligned
      } else {
        unsigned short* Cb = (unsigned short*)Cv + cOff;
        #pragma unroll
        for (int q = 0; q < 4; q++) Cb[(long)(r + q)*ldc + c] = f2bf(v[q] + bv);
      }
    }
  }
}

// ---------------------------------------------------------------------------
// x fp32 (B,512,4096) -> xT bf16 (B,4096,512)    64x64 tiles through LDS
// ---------------------------------------------------------------------------
__global__ void transpose_xT(const float* __restrict__ x, unsigned short* __restrict__ xT)
{
  __shared__ __attribute__((aligned(16))) unsigned short t[64][72];
  const int tid = threadIdx.x;
  const int b = blockIdx.z, ct = blockIdx.y, pt = blockIdx.x;
  const long c0 = (long)ct*64, p0 = (long)pt*64;
  const float* src = x + ((long)b*512 + c0)*4096 + p0;
  for (int s = tid; s < 1024; s += 256){
    int cl = s >> 4, seg = s & 15;
    f32x4 v = *(const f32x4*)(src + (long)cl*4096 + seg*4);
    us4 o;
    #pragma unroll
    for (int q = 0; q < 4; q++) o[q] = f2bf(v[q]);
    *(us4*)(&t[cl][seg*4]) = o;
  }
  __syncthreads();
  unsigned short* dst = xT + ((long)b*4096 + p0)*512 + c0;
  for (int s = tid; s < 512; s += 256){
    int pl = s >> 3, seg = s & 7;
    unsigned short w[8];
    #pragma unroll
    for (int q = 0; q < 8; q++) w[q] = t[seg*8 + q][pl];
    *(bf16x8*)(dst + (long)pl*512 + seg*8) = *(bf16x8*)w;
  }
}

// ---------------------------------------------------------------------------
// AvgPool2d(2,2) on xT: xT (B,4096,512) -> xp (B,1024,512)   (bf16)
// ---------------------------------------------------------------------------
__global__ void pool_xT(const unsigned short* __restrict__ xT, unsigned short* __restrict__ xp)
{
  long idx = (long)blockIdx.x*256 + threadIdx.x;
  int cseg = (int)(idx & 63);
  int m    = (int)((idx >> 6) & 1023);
  int b    = (int)(idx >> 16);
  int gh = m >> 5, gw = m & 31;
  long p = (long)(gh*2)*64 + gw*2;
  const unsigned short* src = xT + ((long)b*4096 + p)*512 + cseg*8;
  bf16x8 r0 = *(const bf16x8*)(src);
  bf16x8 r1 = *(const bf16x8*)(src + 512);
  bf16x8 r2 = *(const bf16x8*)(src + 64*512);
  bf16x8 r3 = *(const bf16x8*)(src + 65*512);
  unsigned short o[8];
  #pragma unroll
  for (int q = 0; q < 8; q++)
    o[q] = f2bf((bf2f((unsigned short)r0[q]) + bf2f((unsigned short)r1[q]) +
                 bf2f((unsigned short)r2[q]) + bf2f((unsigned short)r3[q])) * 0.25f);
  *(bf16x8*)(xp + ((long)b*1024 + m)*512 + cseg*8) = *(bf16x8*)o;
}

// ---------------------------------------------------------------------------
// lkv (B,1024,512) V-half -> vT (B*4, 64, 1024), columns stored in pi-order
// within each 64-kv tile: stored col c holds kv = pi^-1(c) where
//   pi(kv=nj*16+lg*4+rg) = (nj&1)*32 + lg*8 + (nj>>1)*4 + rg
//   pi^-1(c) = ((c>>5)&1)*16 + ((c>>2)&1)*32 + ((c>>3)&3)*4 + (c&3)
// (lofi packs P in-register in pi order; PV dot is order-invariant as long as
//  P slots and V columns share the permutation.)
// ---------------------------------------------------------------------------
__global__ void transpose_vT(const unsigned short* __restrict__ lkv, unsigned short* __restrict__ vT)
{
  __shared__ __attribute__((aligned(16))) unsigned short t[64][72];
  const int tid = threadIdx.x;
  const int pair = blockIdx.y;              // b*4+n
  const int b = pair >> 2, n = pair & 3;
  const long m0 = (long)blockIdx.x*64;      // 64-aligned kv tile base
  const unsigned short* src = lkv + ((long)b*1024 + m0)*512 + 256 + n*64;
  for (int s = tid; s < 512; s += 256){
    int ml = s >> 3, seg = s & 7;
    bf16x8 v = *(const bf16x8*)(src + (long)ml*512 + seg*8);
    *(bf16x8*)(&t[ml][seg*8]) = v;
  }
  __syncthreads();
  unsigned short* dst = vT + (long)pair*64*1024 + m0;
  for (int s = tid; s < 512; s += 256){
    int dl = s >> 3, seg = s & 7;
    unsigned short w[8];
    #pragma unroll
    for (int q = 0; q < 8; q++){
      int c = seg*8 + q;
      int kvi = ((c >> 5) & 1)*16 + ((c >> 2) & 1)*32 + ((c >> 3) & 3)*4 + (c & 3);
      w[q] = t[kvi][dl];
    }
    *(bf16x8*)(dst + (long)dl*1024 + seg*8) = *(bf16x8*)w;
  }
}

// ---------------------------------------------------------------------------
// Hi-fi window attention, batched over blockIdx.y batches.
// ---------------------------------------------------------------------------
__global__ void hifi_attn(const unsigned short* __restrict__ qkv, unsigned short* __restrict__ out)
{
  const int gwv  = (int)((blockIdx.x*blockDim.x + threadIdx.x) >> 6);
  const int lane = threadIdx.x & 63;
  const int n = gwv & 3;
  const int g = gwv >> 2;
  const long bb = (long)blockIdx.y;
  const unsigned short* base = qkv + bb*4096*768 + (long)g*4*768 + n*64 + lane;
  float q[4], k[4], v[4];
  #pragma unroll
  for (int t = 0; t < 4; t++){
    q[t] = bf2f(base[t*768]);
    k[t] = bf2f(base[t*768 + 256]);
    v[t] = bf2f(base[t*768 + 512]);
  }
  float S[4][4];
  #pragma unroll
  for (int i = 0; i < 4; i++)
    #pragma unroll
    for (int j = 0; j < 4; j++){
      float s = q[i]*k[j];
      #pragma unroll
      for (int off = 32; off; off >>= 1) s += __shfl_xor(s, off);
      S[i][j] = s;
    }
  const int gh = g >> 5, gwd = g & 31;
  unsigned short* ob = out + bb*4096*256 + n*64 + lane;
  #pragma unroll
  for (int t = 0; t < 4; t++){
    float m = fmaxf(fmaxf(S[t][0], S[t][1]), fmaxf(S[t][2], S[t][3]));
    float e0 = __expf((S[t][0]-m)*0.125f);
    float e1 = __expf((S[t][1]-m)*0.125f);
    float e2 = __expf((S[t][2]-m)*0.125f);
    float e3 = __expf((S[t][3]-m)*0.125f);
    float inv = 1.f / (e0+e1+e2+e3);
    float o = (e0*v[0] + e1*v[1] + e2*v[2] + e3*v[3]) * inv;
    int y = gh*2 + (t >> 1), xx = gwd*2 + (t & 1);
    ob[(long)(y*64 + xx)*256] = f2bf(o);
  }
}

// ---------------------------------------------------------------------------
// Fused lo-fi flash attention. Grid (32 q-tiles, 32 pairs), 256 threads.
// Swapped QK^T: S = mfma(K,Q) -> lane holds P[q=mi*16+lr][kv=nj*16+lg*4+rg].
// P packed in-register (v_cvt_pk) into PV A-frags in pi order; V columns are
// pi-ordered by transpose_vT. No P LDS traffic. Deferred softmax (bounded
// logits): psum reduced once at the end (2 shfl_xor + broadcast shfl).
// ---------------------------------------------------------------------------
__global__ __launch_bounds__(256, 3)
void lofi_flash(const unsigned short* __restrict__ lq,
                const unsigned short* __restrict__ lkv,
                const unsigned short* __restrict__ vT,
                unsigned short* __restrict__ attnl)
{
  __shared__ __attribute__((aligned(16))) unsigned short Klds[64*64];
  __shared__ __attribute__((aligned(16))) unsigned short Vlds[64*64];
  const int tid  = threadIdx.x;
  const int lane = tid & 63;
  const int wave = tid >> 6;
  const int pair = blockIdx.y;              // b*4+n
  const int b = pair >> 2, n = pair & 3;
  const int wq0 = (int)blockIdx.x*128 + wave*32;
  const int lr = lane & 15;
  const int lg = lane >> 4;

  const unsigned short* Qbase = lq + ((long)b*4096 + wq0)*256 + n*64;
  bf16x8 qf[2][2];
  #pragma unroll
  for (int mi = 0; mi < 2; mi++)
    #pragma unroll
    for (int kk = 0; kk < 2; kk++)
      qf[mi][kk] = *(const bf16x8*)(Qbase + (long)(mi*16 + lr)*256 + kk*32 + lg*8);

  f32x4 Oacc[2][4] = {};
  float psum[2] = {};                       // per-lane partial row sums (q=mi*16+lr)

  const unsigned short* Kg = lkv + (long)b*1024*512 + n*64;
  const unsigned short* Vg = vT + (long)pair*64*1024;

  // async reg-staged K/V: each thread owns rows (rK, rK+32), seg sg
  const int rK = tid >> 3;
  const int sg = (tid & 7) * 8;
  bf16x8 k0, k1, v0, v1;
  {
    k0 = *(const bf16x8*)(Kg + (long)rK*512 + sg);
    k1 = *(const bf16x8*)(Kg + (long)(rK + 32)*512 + sg);
    v0 = *(const bf16x8*)(Vg + (long)rK*1024 + sg);
    v1 = *(const bf16x8*)(Vg + (long)(rK + 32)*1024 + sg);
  }

  for (int t = 0; t < 16; t++){
    __syncthreads();
    *(bf16x8*)(&Klds[swz(rK, sg)])      = k0;
    *(bf16x8*)(&Klds[swz(rK + 32, sg)]) = k1;
    *(bf16x8*)(&Vlds[swz(rK, sg)])      = v0;
    *(bf16x8*)(&Vlds[swz(rK + 32, sg)]) = v1;
    __syncthreads();
    if (t < 15){
      const int kv1 = (t + 1)*64;
      k0 = *(const bf16x8*)(Kg + (long)(kv1 + rK)*512 + sg);
      k1 = *(const bf16x8*)(Kg + (long)(kv1 + rK + 32)*512 + sg);
      v0 = *(const bf16x8*)(Vg + (long)rK*1024 + kv1 + sg);
      v1 = *(const bf16x8*)(Vg + (long)(rK + 32)*1024 + kv1 + sg);
    }
    // S = K @ Q^T (swapped): S[nj][mi], lane holds q=mi*16+lr, kv=nj*16+lg*4+rg
    f32x4 S[4][2] = {};
    bf16x8 kf[4][2];
    #pragma unroll
    for (int nj = 0; nj < 4; nj++)
      #pragma unroll
      for (int kk = 0; kk < 2; kk++)
        kf[nj][kk] = *(const bf16x8*)(&Klds[swz(nj*16 + lr, kk*32 + lg*8)]);
    #pragma unroll
    for (int nj = 0; nj < 4; nj++)
      #pragma unroll
      for (int mi = 0; mi < 2; mi++)
        #pragma unroll
        for (int kk = 0; kk < 2; kk++)
          S[nj][mi] = __builtin_amdgcn_mfma_f32_16x16x32_bf16(kf[nj][kk], qf[mi][kk], S[nj][mi], 0, 0, 0);
    // P = exp2(S*c) packed in-register into PV A-frags (pi order):
    // pf[mi][kk=nj&1] word (nj>>1)*2 + rg/2.
    bf16x8 pf[2][2];
    #pragma unroll
    for (int mi = 0; mi < 2; mi++){
      float ps = 0.f;
      unsigned int w[8];
      #pragma unroll
      for (int nj = 0; nj < 4; nj++){
        float e0 = exp2f(S[nj][mi][0]*0.1803368801f);
        float e1 = exp2f(S[nj][mi][1]*0.1803368801f);
        float e2 = exp2f(S[nj][mi][2]*0.1803368801f);
        float e3 = exp2f(S[nj][mi][3]*0.1803368801f);
        ps += (e0 + e1) + (e2 + e3);
        unsigned int lo, hi;
        asm("v_cvt_pk_bf16_f32 %0, %1, %2" : "=v"(lo) : "v"(e0), "v"(e1));
        asm("v_cvt_pk_bf16_f32 %0, %1, %2" : "=v"(hi) : "v"(e2), "v"(e3));
        w[(nj & 1)*4 + (nj >> 1)*2]     = lo;
        w[(nj & 1)*4 + (nj >> 1)*2 + 1] = hi;
      }
      psum[mi] += ps;
      u32x4 a0, a1;
      a0[0] = w[0]; a0[1] = w[1]; a0[2] = w[2]; a0[3] = w[3];
      a1[0] = w[4]; a1[1] = w[5]; a1[2] = w[6]; a1[3] = w[7];
      __builtin_memcpy(&pf[mi][0], &a0, 16);
      __builtin_memcpy(&pf[mi][1], &a1, 16);
    }
    // PV: O += P @ V  (A=P rows q, B=V^T rows d; k in shared pi order)
    bf16x8 vf[4][2];
    #pragma unroll
    for (int dj = 0; dj < 4; dj++)
      #pragma unroll
      for (int kk = 0; kk < 2; kk++)
        vf[dj][kk] = *(const bf16x8*)(&Vlds[swz(dj*16 + lr, kk*32 + lg*8)]);
    #pragma unroll
    for (int mi = 0; mi < 2; mi++)
      #pragma unroll
      for (int dj = 0; dj < 4; dj++)
        #pragma unroll
        for (int kk = 0; kk < 2; kk++)
          Oacc[mi][dj] = __builtin_amdgcn_mfma_f32_16x16x32_bf16(pf[mi][kk], vf[dj][kk], Oacc[mi][dj], 0, 0, 0);
  }
  // full row-sum: reduce psum across the 4 lg groups (lanes lr, lr+16, ...)
  #pragma unroll
  for (int mi = 0; mi < 2; mi++){
    float s = psum[mi];
    s += __shfl_xor(s, 16);
    s += __shfl_xor(s, 32);
    psum[mi] = s;                           // valid at q = mi*16 + lr (all lg)
  }
  // epilogue: Oacc[mi][dj][rg] is q = mi*16 + lg*4 + rg; fetch 1/l via shfl
  unsigned short* Ob = attnl + ((long)b*4096 + wq0)*256 + n*64;
  #pragma unroll
  for (int mi = 0; mi < 2; mi++)
    #pragma unroll
    for (int rg = 0; rg < 4; rg++){
      float l = __shfl(psum[mi], lg*4 + rg);   // lane lg*4+rg holds full sum
      float inv = 1.f / l;
      int r = mi*16 + lg*4 + rg;
      #pragma unroll
      for (int dj = 0; dj < 4; dj++)
        Ob[(long)r*256 + dj*16 + lr] = f2bf(Oacc[mi][dj][rg] * inv);
    }
}

// ---------------------------------------------------------------------------
extern "C" void kernel_launch(void* const* d_in, const int* in_sizes, int n_in,
                              void* d_out, int out_size, void* d_ws, size_t ws_size,
                              hipStream_t stream)
{
  (void)in_sizes; (void)n_in; (void)out_size;
  const float* x      = (const float*)d_in[0];
  const float* Whqkv  = (const float*)d_in[1];
  const float* bhqkv  = (const float*)d_in[2];
  const float* Whproj = (const float*)d_in[3];
  const float* bhproj = (const float*)d_in[4];
  const float* Wlq    = (const float*)d_in[5];
  const float* blq    = (const float*)d_in[6];
  const float* Wlkv   = (const float*)d_in[7];
  const float* blkv   = (const float*)d_in[8];
  const float* Wlproj = (const float*)d_in[9];
  const float* blproj = (const float*)d_in[10];
  float* out = (float*)d_out;
  char* ws = (char*)d_ws;

  // Layout (bytes), peak touched 73,138,176 (same guard as green R7):
  if (ws_size < 73138176u) return;
  unsigned short* xT      = (unsigned short*)(ws + 0);
  unsigned short* attnl   = (unsigned short*)(ws + 0);
  unsigned short* qkvh_c  = (unsigned short*)(ws + 33554432L);
  unsigned short* attnh_c = (unsigned short*)(ws + 58720256L);
  unsigned short* lqb     = (unsigned short*)(ws + 33554432L);
  unsigned short* xp      = (unsigned short*)(ws + 50331648L);
  unsigned short* lkvb    = (unsigned short*)(ws + 58720256L);
  unsigned short* vTb     = (unsigned short*)(ws + 67108864L);
  unsigned short* Whqkv_b = (unsigned short*)(ws + 71303168L);
  unsigned short* Wlq_b   = (unsigned short*)(ws + 72089600L);
  unsigned short* Wlkv_b  = (unsigned short*)(ws + 72351744L);
  unsigned short* Whproj_b= (unsigned short*)(ws + 72876032L);
  unsigned short* Wlproj_b= (unsigned short*)(ws + 73007104L);

  // 0) all weights fp32 -> bf16 (one launch)
  cvt_weights<<<896, 256, 0, stream>>>(Whqkv, Wlq, Wlkv, Whproj, Wlproj,
                                       Whqkv_b, Wlq_b, Wlkv_b, Whproj_b, Wlproj_b);

  // 1) x -> xT (spatial-major, bf16)
  transpose_xT<<<dim3(64,8,8),256,0,stream>>>(x, xT);

  // 2) hi-fi path, 2 chunks of 4 batches
  for (int c = 0; c < 2; c++){
    const unsigned short* xTc = xT + (long)c*4*4096*512;
    gemm_bt<128,128,2,2,false,false><<<dim3(32,6,4),256,0,stream>>>(xTc, Whqkv_b, bhqkv, qkvh_c,
        512, 512, 512, 768, 1, 0,
        0, 0, 4096L*512,   0, 0, 0,   0, 0, 4096L*768);
    hifi_attn<<<dim3(1024,4),256,0,stream>>>(qkvh_c, attnh_c);
    gemm_bt<128,128,2,2,true,true><<<dim3(32,2,4),256,0,stream>>>(attnh_c, Whproj_b, bhproj,
        out + (long)c*4*512*4096,
        256, 256, 256, 4096, 1, 0,
        0, 0, 4096L*256,   0, 0, 0,   0, 0, 512L*4096);
  }

  // 3) lq = xT @ W_lq^T + b   (B,4096,256)
  gemm_bt<128,128,2,2,false,false><<<dim3(32,2,8),256,0,stream>>>(xT, Wlq_b, blq, lqb,
      512, 512, 512, 256, 1, 0,
      4096L*512, 0, 0,   0, 0, 0,   4096L*256, 0, 0);
  // 4) avgpool -> xp (B,1024,512)
  pool_xT<<<2048,256,0,stream>>>(xT, xp);
  // 5) lkv = xp @ W_lkv^T + b (B,1024,512)
  gemm_bt<128,128,2,2,false,false><<<dim3(8,4,8),256,0,stream>>>(xp, Wlkv_b, blkv, lkvb,
      512, 512, 512, 512, 1, 0,
      1024L*512, 0, 0,   0, 0, 0,   1024L*512, 0, 0);
  // 6) V^T per (b,head), pi-ordered columns: (32,64,1024)
  transpose_vT<<<dim3(16,32),256,0,stream>>>(lkvb, vTb);
  // 7) lo-fi flash attention (xT dead -> attnl region)
  lofi_flash<<<dim3(32,32),256,0,stream>>>(lqb, lkvb, vTb, attnl);
  // 8) x_l = attnl @ W_lproj^T + b -> d_out channels [256,512), batched
  gemm_bt<128,128,2,2,true,true><<<dim3(32,2,8),256,0,stream>>>(attnl, Wlproj_b, blproj,
      out + 256L*4096,
      256, 256, 256, 4096, 1, 0,
      4096L*256, 0, 0,   0, 0, 0,   512L*4096, 0, 0);
}